// Round 3
// baseline (586.157 us; speedup 1.0000x reference)
//
#include <hip/hip_runtime.h>

typedef __bf16 bf16;
typedef __bf16 bf16x4 __attribute__((ext_vector_type(4)));
typedef __bf16 bf16x8 __attribute__((ext_vector_type(8)));
typedef float f32x4 __attribute__((ext_vector_type(4)));

#define LOG2E 1.4426950408889634f

constexpr int Bsz = 8, N = 2048, IN = 256, H = 8, D = 64;
constexpr int M = Bsz * N;       // 16384 rows
constexpr int HD = H * D;        // 512
constexpr int QKV = 3 * HD;      // 1536

// ---------------- prep kernels ----------------
__global__ void cvt_msg(const float* __restrict__ in, bf16* __restrict__ out) {
    int i = blockIdx.x * blockDim.x + threadIdx.x;   // one float4 per thread
    float4 v = ((const float4*)in)[i];
    bf16x4 o = { (bf16)v.x, (bf16)v.y, (bf16)v.z, (bf16)v.w };
    ((bf16x4*)out)[i] = o;
}

__global__ void pack_w(const float* __restrict__ Wq, const float* __restrict__ Wk,
                       const float* __restrict__ Wv, const float* __restrict__ bq,
                       const float* __restrict__ bk, const float* __restrict__ bv,
                       const float* __restrict__ Wo,
                       bf16* __restrict__ Wt, float* __restrict__ bias,
                       bf16* __restrict__ Wot) {
    int idx = blockIdx.x * 256 + threadIdx.x;
    if (idx < QKV * IN) {                 // Wt[c][k] = W(k, c%512), c-major
        int c = idx / IN, k = idx - c * IN;
        const float* W = (c < HD) ? Wq : (c < 2 * HD ? Wk : Wv);
        Wt[idx] = (bf16)W[k * HD + (c & (HD - 1))];
        return;
    }
    idx -= QKV * IN;
    if (idx < D * HD) {                   // Wot[d][c] = Wo[c][d]
        int d = idx / HD, c = idx - d * HD;
        Wot[idx] = (bf16)Wo[c * D + d];
        return;
    }
    idx -= D * HD;
    if (idx < QKV) {
        bias[idx] = (idx < HD) ? bq[idx] : (idx < 2 * HD ? bk[idx - HD] : bv[idx - 2 * HD]);
    }
}

// ---------------- QKV projection GEMM ----------------
// C[m][c] = A[m][:] . Wt[c][:] + bias[c];  scatter into Q,K ([B,H,N,D]) and Vt ([B,H,D,N])
__global__ __launch_bounds__(256) void qkv_gemm(
    const bf16* __restrict__ A, const bf16* __restrict__ Wt,
    const float* __restrict__ bias,
    bf16* __restrict__ Q, bf16* __restrict__ K, bf16* __restrict__ Vt) {
    const int w = threadIdx.x >> 6, lane = threadIdx.x & 63;
    const int lr = lane & 15, lg = lane >> 4;
    const int m0 = blockIdx.x * 128 + w * 32;
    const int c0 = blockIdx.y * 128;

    f32x4 acc[2][8] = {};
    const bf16* ap0 = A + (size_t)(m0 + lr) * IN + lg * 8;
    const bf16* ap1 = A + (size_t)(m0 + 16 + lr) * IN + lg * 8;
    const bf16* bp  = Wt + (size_t)(c0 + lr) * IN + lg * 8;

#pragma unroll
    for (int ks = 0; ks < 8; ++ks) {
        bf16x8 a0 = *(const bf16x8*)(ap0 + ks * 32);
        bf16x8 a1 = *(const bf16x8*)(ap1 + ks * 32);
#pragma unroll
        for (int nt = 0; nt < 8; ++nt) {
            bf16x8 bf = *(const bf16x8*)(bp + (size_t)nt * 16 * IN + ks * 32);
            acc[0][nt] = __builtin_amdgcn_mfma_f32_16x16x32_bf16(a0, bf, acc[0][nt], 0, 0, 0);
            acc[1][nt] = __builtin_amdgcn_mfma_f32_16x16x32_bf16(a1, bf, acc[1][nt], 0, 0, 0);
        }
    }

#pragma unroll
    for (int mt = 0; mt < 2; ++mt) {
        int rowb = m0 + mt * 16 + lg * 4;
#pragma unroll
        for (int nt = 0; nt < 8; ++nt) {
            int col = c0 + nt * 16 + lr;
            float bv = bias[col];
            int which = col >> 9;       // 0=Q 1=K 2=V
            int cc = col & (HD - 1);
            int h = cc >> 6, d = cc & 63;
#pragma unroll
            for (int r = 0; r < 4; ++r) {
                float v = acc[mt][nt][r] + bv;
                int row = rowb + r;
                int b = row >> 11, n = row & (N - 1);
                if (which == 0)      Q[(((size_t)(b * H + h) * N) + n) * D + d] = (bf16)v;
                else if (which == 1) K[(((size_t)(b * H + h) * N) + n) * D + d] = (bf16)v;
                else                 Vt[((size_t)(b * H + h) * D + d) * N + n] = (bf16)v;
            }
        }
    }
}

// ---------------- fused attention (flash-style) ----------------
__device__ __forceinline__ float rmax16(float v) {
    v = fmaxf(v, __shfl_xor(v, 1));
    v = fmaxf(v, __shfl_xor(v, 2));
    v = fmaxf(v, __shfl_xor(v, 4));
    v = fmaxf(v, __shfl_xor(v, 8));
    return v;
}
__device__ __forceinline__ float rsum16(float v) {
    v += __shfl_xor(v, 1);
    v += __shfl_xor(v, 2);
    v += __shfl_xor(v, 4);
    v += __shfl_xor(v, 8);
    return v;
}

__global__ __launch_bounds__(256) void attn_kernel(
    const bf16* __restrict__ Qg, const bf16* __restrict__ Kg,
    const bf16* __restrict__ Vtg, bf16* __restrict__ ctx) {
    __shared__ bf16 P[4][32][72];   // padded: stride 144B -> only 2-way bank aliasing
    const int w = threadIdx.x >> 6, lane = threadIdx.x & 63;
    const int lr = lane & 15, lg = lane >> 4;
    const int bh = blockIdx.x;
    const int q0 = blockIdx.y * 128 + w * 32;

    const bf16* Qp = Qg + (size_t)bh * N * D;
    const bf16* Kp = Kg + (size_t)bh * N * D;
    const bf16* Vp = Vtg + (size_t)bh * D * N;

    bf16x8 qf[2][2];
#pragma unroll
    for (int mt = 0; mt < 2; ++mt)
#pragma unroll
        for (int ks = 0; ks < 2; ++ks)
            qf[mt][ks] = *(const bf16x8*)(Qp + (size_t)(q0 + mt * 16 + lr) * D + ks * 32 + lg * 8);

    float mrow[2][4], lrow[2][4];
    f32x4 cacc[2][4] = {};
#pragma unroll
    for (int mt = 0; mt < 2; ++mt)
#pragma unroll
        for (int r = 0; r < 4; ++r) { mrow[mt][r] = -1e30f; lrow[mt][r] = 0.f; }

    for (int kt = 0; kt < N / 64; ++kt) {
        const int kk0 = kt * 64;
        // ---- S = Q K^T
        f32x4 s[2][4] = {};
#pragma unroll
        for (int nt = 0; nt < 4; ++nt)
#pragma unroll
            for (int ks = 0; ks < 2; ++ks) {
                bf16x8 kf = *(const bf16x8*)(Kp + (size_t)(kk0 + nt * 16 + lr) * D + ks * 32 + lg * 8);
                s[0][nt] = __builtin_amdgcn_mfma_f32_16x16x32_bf16(qf[0][ks], kf, s[0][nt], 0, 0, 0);
                s[1][nt] = __builtin_amdgcn_mfma_f32_16x16x32_bf16(qf[1][ks], kf, s[1][nt], 0, 0, 0);
            }
        // ---- scale + exclude-self mask + row max
        float rmax[2][4];
#pragma unroll
        for (int mt = 0; mt < 2; ++mt)
#pragma unroll
            for (int r = 0; r < 4; ++r) rmax[mt][r] = -3e38f;
#pragma unroll
        for (int mt = 0; mt < 2; ++mt)
#pragma unroll
            for (int nt = 0; nt < 4; ++nt)
#pragma unroll
                for (int r = 0; r < 4; ++r) {
                    float v = s[mt][nt][r] * 0.125f;
                    int ra = q0 + mt * 16 + lg * 4 + r;
                    int ca = kk0 + nt * 16 + lr;
                    if (ra == ca) v = -1e9f;
                    s[mt][nt][r] = v;
                    rmax[mt][r] = fmaxf(rmax[mt][r], v);
                }
        float fac[2][4];
#pragma unroll
        for (int mt = 0; mt < 2; ++mt)
#pragma unroll
            for (int r = 0; r < 4; ++r) {
                float rm = rmax16(rmax[mt][r]);
                float mn = fmaxf(mrow[mt][r], rm);
                fac[mt][r] = exp2f((mrow[mt][r] - mn) * LOG2E);
                mrow[mt][r] = mn;
            }
        // ---- P = exp(S - m), write to LDS, row sums
        float psum[2][4] = {};
#pragma unroll
        for (int mt = 0; mt < 2; ++mt)
#pragma unroll
            for (int nt = 0; nt < 4; ++nt)
#pragma unroll
                for (int r = 0; r < 4; ++r) {
                    float p = exp2f((s[mt][nt][r] - mrow[mt][r]) * LOG2E);
                    psum[mt][r] += p;
                    P[w][mt * 16 + lg * 4 + r][nt * 16 + lr] = (bf16)p;
                }
#pragma unroll
        for (int mt = 0; mt < 2; ++mt)
#pragma unroll
            for (int r = 0; r < 4; ++r) {
                float ps = rsum16(psum[mt][r]);
                lrow[mt][r] = lrow[mt][r] * fac[mt][r] + ps;
            }
        // ---- rescale accumulator
#pragma unroll
        for (int mt = 0; mt < 2; ++mt)
#pragma unroll
            for (int dt = 0; dt < 4; ++dt)
#pragma unroll
                for (int r = 0; r < 4; ++r) cacc[mt][dt][r] *= fac[mt][r];
        // ---- ctx += P V   (Vt rows are contiguous along kk)
#pragma unroll
        for (int ks = 0; ks < 2; ++ks) {
            bf16x8 pa[2];
#pragma unroll
            for (int mt = 0; mt < 2; ++mt)
                pa[mt] = *(const bf16x8*)(&P[w][mt * 16 + lr][ks * 32 + lg * 8]);
#pragma unroll
            for (int dt = 0; dt < 4; ++dt) {
                bf16x8 vf = *(const bf16x8*)(Vp + (size_t)(dt * 16 + lr) * N + kk0 + ks * 32 + lg * 8);
                cacc[0][dt] = __builtin_amdgcn_mfma_f32_16x16x32_bf16(pa[0], vf, cacc[0][dt], 0, 0, 0);
                cacc[1][dt] = __builtin_amdgcn_mfma_f32_16x16x32_bf16(pa[1], vf, cacc[1][dt], 0, 0, 0);
            }
        }
    }
    // ---- epilogue: ctx[b][n][h*64+d]
    const int b = bh >> 3, h = bh & 7;
#pragma unroll
    for (int mt = 0; mt < 2; ++mt)
#pragma unroll
        for (int r = 0; r < 4; ++r) {
            int ra = q0 + mt * 16 + lg * 4 + r;
            float ool = 1.0f / lrow[mt][r];
#pragma unroll
            for (int dt = 0; dt < 4; ++dt)
                ctx[((size_t)(b * N + ra)) * HD + h * 64 + dt * 16 + lr] =
                    (bf16)(cacc[mt][dt][r] * ool);
        }
}

// ---------------- output projection ----------------
__global__ __launch_bounds__(256) void out_gemm(
    const bf16* __restrict__ ctx, const bf16* __restrict__ Wot,
    float* __restrict__ out) {
    const int w = threadIdx.x >> 6, lane = threadIdx.x & 63;
    const int lr = lane & 15, lg = lane >> 4;
    const int m0 = blockIdx.x * 64 + w * 16;
    f32x4 acc[4] = {};
#pragma unroll
    for (int ks = 0; ks < 16; ++ks) {
        bf16x8 af = *(const bf16x8*)(ctx + (size_t)(m0 + lr) * HD + ks * 32 + lg * 8);
#pragma unroll
        for (int nt = 0; nt < 4; ++nt) {
            bf16x8 wf = *(const bf16x8*)(Wot + (size_t)(nt * 16 + lr) * HD + ks * 32 + lg * 8);
            acc[nt] = __builtin_amdgcn_mfma_f32_16x16x32_bf16(af, wf, acc[nt], 0, 0, 0);
        }
    }
#pragma unroll
    for (int nt = 0; nt < 4; ++nt)
#pragma unroll
        for (int r = 0; r < 4; ++r)
            out[(size_t)(m0 + lg * 4 + r) * D + nt * 16 + lr] = acc[nt][r];
}

// ---------------- launcher ----------------
extern "C" void kernel_launch(void* const* d_in, const int* in_sizes, int n_in,
                              void* d_out, int out_size, void* d_ws, size_t ws_size,
                              hipStream_t stream) {
    (void)in_sizes; (void)n_in; (void)out_size; (void)ws_size;
    const float* msg = (const float*)d_in[0];
    const float* Wq  = (const float*)d_in[1];
    const float* bq  = (const float*)d_in[2];
    const float* Wk  = (const float*)d_in[3];
    const float* bk  = (const float*)d_in[4];
    const float* Wv  = (const float*)d_in[5];
    const float* bv  = (const float*)d_in[6];
    const float* Wo  = (const float*)d_in[7];
    float* out = (float*)d_out;

    char* p = (char*)d_ws;
    bf16*  Abf  = (bf16*)p;  p += (size_t)M * IN * 2;      // 8 MB
    bf16*  Wt   = (bf16*)p;  p += (size_t)QKV * IN * 2;    // 768 KB
    float* bias = (float*)p; p += (size_t)QKV * 4;         // 6 KB
    bf16*  Wot  = (bf16*)p;  p += (size_t)D * HD * 2;      // 64 KB
    bf16*  Qb   = (bf16*)p;  p += (size_t)Bsz * H * N * D * 2;   // 16 MB
    bf16*  Kb   = (bf16*)p;  p += (size_t)Bsz * H * N * D * 2;   // 16 MB
    bf16*  Vtb  = (bf16*)p;  p += (size_t)Bsz * H * D * N * 2;   // 16 MB
    bf16*  Ctx  = (bf16*)p;  p += (size_t)M * HD * 2;            // 16 MB

    cvt_msg<<<(M * IN / 4) / 256, 256, 0, stream>>>(msg, Abf);
    pack_w<<<(QKV * IN + D * HD + QKV + 255) / 256, 256, 0, stream>>>(
        Wq, Wk, Wv, bq, bk, bv, Wo, Wt, bias, Wot);

    dim3 g1(M / 128, QKV / 128);     // 128 x 12
    qkv_gemm<<<g1, 256, 0, stream>>>(Abf, Wt, bias, Qb, Kb, Vtb);

    dim3 g2(Bsz * H, N / 128);       // 64 x 16 : same-bh blocks land on same XCD
    attn_kernel<<<g2, 256, 0, stream>>>(Qb, Kb, Vtb, Ctx);

    out_gemm<<<M / 64, 256, 0, stream>>>(Ctx, Wot, out);
}

// Round 4
// 408.924 us; speedup vs baseline: 1.4334x; 1.4334x over previous
//
#include <hip/hip_runtime.h>

typedef __bf16 bf16;
typedef __bf16 bf16x4 __attribute__((ext_vector_type(4)));
typedef __bf16 bf16x8 __attribute__((ext_vector_type(8)));
typedef float f32x4 __attribute__((ext_vector_type(4)));

#define SCLOG 0.1803368801111244f   // 0.125 * log2(e)

constexpr int Bsz = 8, N = 2048, IN = 256, H = 8, D = 64;
constexpr int M = Bsz * N;       // 16384 rows
constexpr int HD = H * D;        // 512
constexpr int QKV = 3 * HD;      // 1536

// ---------------- prep kernels ----------------
__global__ void cvt_msg(const float* __restrict__ in, bf16* __restrict__ out) {
    int i = blockIdx.x * blockDim.x + threadIdx.x;   // one float4 per thread
    float4 v = ((const float4*)in)[i];
    bf16x4 o = { (bf16)v.x, (bf16)v.y, (bf16)v.z, (bf16)v.w };
    ((bf16x4*)out)[i] = o;
}

__global__ void pack_w(const float* __restrict__ Wq, const float* __restrict__ Wk,
                       const float* __restrict__ Wv, const float* __restrict__ bq,
                       const float* __restrict__ bk, const float* __restrict__ bv,
                       const float* __restrict__ Wo,
                       bf16* __restrict__ Wt, float* __restrict__ bias,
                       bf16* __restrict__ Wot) {
    int idx = blockIdx.x * 256 + threadIdx.x;
    if (idx < QKV * IN) {                 // Wt[c][k] = W(k, c%512), c-major
        int c = idx / IN, k = idx - c * IN;
        const float* W = (c < HD) ? Wq : (c < 2 * HD ? Wk : Wv);
        Wt[idx] = (bf16)W[k * HD + (c & (HD - 1))];
        return;
    }
    idx -= QKV * IN;
    if (idx < D * HD) {                   // Wot[d][c] = Wo[c][d]
        int d = idx / HD, c = idx - d * HD;
        Wot[idx] = (bf16)Wo[c * D + d];
        return;
    }
    idx -= D * HD;
    if (idx < QKV) {
        bias[idx] = (idx < HD) ? bq[idx] : (idx < 2 * HD ? bk[idx - HD] : bv[idx - 2 * HD]);
    }
}

// ---------------- QKV projection GEMM ----------------
__global__ __launch_bounds__(256) void qkv_gemm(
    const bf16* __restrict__ A, const bf16* __restrict__ Wt,
    const float* __restrict__ bias,
    bf16* __restrict__ Q, bf16* __restrict__ K, bf16* __restrict__ Vt) {
    const int w = threadIdx.x >> 6, lane = threadIdx.x & 63;
    const int lr = lane & 15, lg = lane >> 4;
    const int m0 = blockIdx.x * 128 + w * 32;
    const int c0 = blockIdx.y * 128;

    f32x4 acc[2][8] = {};
    const bf16* ap0 = A + (size_t)(m0 + lr) * IN + lg * 8;
    const bf16* ap1 = A + (size_t)(m0 + 16 + lr) * IN + lg * 8;
    const bf16* bp  = Wt + (size_t)(c0 + lr) * IN + lg * 8;

#pragma unroll
    for (int ks = 0; ks < 8; ++ks) {
        bf16x8 a0 = *(const bf16x8*)(ap0 + ks * 32);
        bf16x8 a1 = *(const bf16x8*)(ap1 + ks * 32);
#pragma unroll
        for (int nt = 0; nt < 8; ++nt) {
            bf16x8 bf = *(const bf16x8*)(bp + (size_t)nt * 16 * IN + ks * 32);
            acc[0][nt] = __builtin_amdgcn_mfma_f32_16x16x32_bf16(a0, bf, acc[0][nt], 0, 0, 0);
            acc[1][nt] = __builtin_amdgcn_mfma_f32_16x16x32_bf16(a1, bf, acc[1][nt], 0, 0, 0);
        }
    }

#pragma unroll
    for (int mt = 0; mt < 2; ++mt) {
        int rowb = m0 + mt * 16 + lg * 4;
#pragma unroll
        for (int nt = 0; nt < 8; ++nt) {
            int col = c0 + nt * 16 + lr;
            float bv = bias[col];
            int which = col >> 9;       // 0=Q 1=K 2=V
            int cc = col & (HD - 1);
            int h = cc >> 6, d = cc & 63;
#pragma unroll
            for (int r = 0; r < 4; ++r) {
                float v = acc[mt][nt][r] + bv;
                int row = rowb + r;
                int b = row >> 11, n = row & (N - 1);
                if (which == 0)      Q[(((size_t)(b * H + h) * N) + n) * D + d] = (bf16)v;
                else if (which == 1) K[(((size_t)(b * H + h) * N) + n) * D + d] = (bf16)v;
                else                 Vt[((size_t)(b * H + h) * D + d) * N + n] = (bf16)v;
            }
        }
    }
}

// ---------------- fused attention (flash-style, swapped QK^T) ----------------
// S^T = mfma(A=K_frag, B=Q_frag): lane holds col q = lane&15 (+16*qt),
// rows k = 16*nt + 4*(lane>>4) + r.  Row-stats lane-local + 2 shuffles.
// P written as b64 (4 consecutive k per q-row), re-read as b128 A-frags for PV.
__global__ __launch_bounds__(256, 4) void attn_kernel(
    const bf16* __restrict__ Qg, const bf16* __restrict__ Kg,
    const bf16* __restrict__ Vtg, bf16* __restrict__ ctx) {
    __shared__ bf16 P[4][32][72];   // 144B row stride: b64 writes ~2-way (free)
    const int w = threadIdx.x >> 6, lane = threadIdx.x & 63;
    const int lr = lane & 15, lg = lane >> 4;
    const int bh = blockIdx.x;
    const int q0 = blockIdx.y * 128 + w * 32;   // wave's 32 q-rows

    const bf16* Qp = Qg + (size_t)bh * N * D;
    const bf16* Kp = Kg + (size_t)bh * N * D;
    const bf16* Vp = Vtg + (size_t)bh * D * N;

    // Q fragments (B-operand): lane holds Q[q0+qt*16+lr][kd*32+lg*8 ..+8]
    bf16x8 qf[2][2];
#pragma unroll
    for (int qt = 0; qt < 2; ++qt)
#pragma unroll
        for (int kd = 0; kd < 2; ++kd)
            qf[qt][kd] = *(const bf16x8*)(Qp + (size_t)(q0 + qt * 16 + lr) * D + kd * 32 + lg * 8);

    float mrow[2] = { -1e30f, -1e30f };   // running max (raw scores) for q = lr + 16*qt
    float lrow[2] = { 0.f, 0.f };
    f32x4 cacc[2][4] = {};                // rows q = 4*lg + r, cols d = dt*16 + lr

    for (int kt = 0; kt < N / 64; ++kt) {
        const int kk0 = kt * 64;
        // ---- S^T = K Q^T  (raw, unscaled)
        f32x4 s[2][4] = {};
#pragma unroll
        for (int nt = 0; nt < 4; ++nt)
#pragma unroll
            for (int kd = 0; kd < 2; ++kd) {
                bf16x8 kf = *(const bf16x8*)(Kp + (size_t)(kk0 + nt * 16 + lr) * D + kd * 32 + lg * 8);
                s[0][nt] = __builtin_amdgcn_mfma_f32_16x16x32_bf16(kf, qf[0][kd], s[0][nt], 0, 0, 0);
                s[1][nt] = __builtin_amdgcn_mfma_f32_16x16x32_bf16(kf, qf[1][kd], s[1][nt], 0, 0, 0);
            }
        // ---- exclude-self mask, only on the <=2 tiles that touch the diagonal
        if (kk0 < q0 + 32 && q0 < kk0 + 64) {
#pragma unroll
            for (int qt = 0; qt < 2; ++qt) {
                int q = q0 + qt * 16 + lr;
#pragma unroll
                for (int nt = 0; nt < 4; ++nt)
#pragma unroll
                    for (int r = 0; r < 4; ++r)
                        if (kk0 + nt * 16 + lg * 4 + r == q) s[qt][nt][r] = -3e38f;
            }
        }
        // ---- row max (raw): 15 in-reg + 2 shuffles; defer-max check
        float rm[2];
        bool need = false;
#pragma unroll
        for (int qt = 0; qt < 2; ++qt) {
            float v = s[qt][0][0];
#pragma unroll
            for (int nt = 0; nt < 4; ++nt)
#pragma unroll
                for (int r = 0; r < 4; ++r) v = fmaxf(v, s[qt][nt][r]);
            v = fmaxf(v, __shfl_xor(v, 16));
            v = fmaxf(v, __shfl_xor(v, 32));
            rm[qt] = v;
            need = need || (v > mrow[qt] + 64.f);   // 64 raw = 8 post-scale
        }
        if (__any(need)) {
#pragma unroll
            for (int qt = 0; qt < 2; ++qt) {
                float mn = fmaxf(mrow[qt], rm[qt]);
                float f = exp2f((mrow[qt] - mn) * SCLOG);
                mrow[qt] = mn;
                lrow[qt] *= f;
                // redistribute f to cacc's row mapping (q = 4*lg + r)
#pragma unroll
                for (int r = 0; r < 4; ++r) {
                    float fr = __shfl(f, lg * 4 + r);
#pragma unroll
                    for (int dt = 0; dt < 4; ++dt) cacc[qt][dt][r] *= fr;
                }
            }
        }
        // ---- P = exp2((s - m)*SCLOG), pack b64 to LDS, row sums
#pragma unroll
        for (int qt = 0; qt < 2; ++qt) {
            float mc = mrow[qt] * SCLOG;
            float ps = 0.f;
#pragma unroll
            for (int nt = 0; nt < 4; ++nt) {
                float p0 = exp2f(__builtin_fmaf(s[qt][nt][0], SCLOG, -mc));
                float p1 = exp2f(__builtin_fmaf(s[qt][nt][1], SCLOG, -mc));
                float p2 = exp2f(__builtin_fmaf(s[qt][nt][2], SCLOG, -mc));
                float p3 = exp2f(__builtin_fmaf(s[qt][nt][3], SCLOG, -mc));
                ps += (p0 + p1) + (p2 + p3);
                bf16x4 pk = { (bf16)p0, (bf16)p1, (bf16)p2, (bf16)p3 };
                *(bf16x4*)&P[w][qt * 16 + lr][nt * 16 + lg * 4] = pk;
            }
            ps += __shfl_xor(ps, 16);
            ps += __shfl_xor(ps, 32);
            lrow[qt] += ps;
        }
        // ---- ctx += P V   (A-frag: P[q=lr+16qt][32ks+8lg ..+8]; B-frag: Vt)
#pragma unroll
        for (int ks = 0; ks < 2; ++ks) {
            bf16x8 pa[2];
#pragma unroll
            for (int qt = 0; qt < 2; ++qt)
                pa[qt] = *(const bf16x8*)(&P[w][qt * 16 + lr][ks * 32 + lg * 8]);
#pragma unroll
            for (int dt = 0; dt < 4; ++dt) {
                bf16x8 vf = *(const bf16x8*)(Vp + (size_t)(dt * 16 + lr) * N + kk0 + ks * 32 + lg * 8);
                cacc[0][dt] = __builtin_amdgcn_mfma_f32_16x16x32_bf16(pa[0], vf, cacc[0][dt], 0, 0, 0);
                cacc[1][dt] = __builtin_amdgcn_mfma_f32_16x16x32_bf16(pa[1], vf, cacc[1][dt], 0, 0, 0);
            }
        }
    }
    // ---- epilogue: ctx[b][n=q][h*64+d];  cacc rows are q = 4*lg + r
    const int b = bh >> 3, h = bh & 7;
#pragma unroll
    for (int qt = 0; qt < 2; ++qt) {
        float ool = 1.0f / lrow[qt];
#pragma unroll
        for (int r = 0; r < 4; ++r) {
            float oolr = __shfl(ool, lg * 4 + r);
            int q = q0 + qt * 16 + lg * 4 + r;
#pragma unroll
            for (int dt = 0; dt < 4; ++dt)
                ctx[((size_t)(b * N + q)) * HD + h * 64 + dt * 16 + lr] =
                    (bf16)(cacc[qt][dt][r] * oolr);
        }
    }
}

// ---------------- output projection ----------------
__global__ __launch_bounds__(256) void out_gemm(
    const bf16* __restrict__ ctx, const bf16* __restrict__ Wot,
    float* __restrict__ out) {
    const int w = threadIdx.x >> 6, lane = threadIdx.x & 63;
    const int lr = lane & 15, lg = lane >> 4;
    const int m0 = blockIdx.x * 64 + w * 16;
    f32x4 acc[4] = {};
#pragma unroll
    for (int ks = 0; ks < 16; ++ks) {
        bf16x8 af = *(const bf16x8*)(ctx + (size_t)(m0 + lr) * HD + ks * 32 + lg * 8);
#pragma unroll
        for (int nt = 0; nt < 4; ++nt) {
            bf16x8 wf = *(const bf16x8*)(Wot + (size_t)(nt * 16 + lr) * HD + ks * 32 + lg * 8);
            acc[nt] = __builtin_amdgcn_mfma_f32_16x16x32_bf16(af, wf, acc[nt], 0, 0, 0);
        }
    }
#pragma unroll
    for (int nt = 0; nt < 4; ++nt)
#pragma unroll
        for (int r = 0; r < 4; ++r)
            out[(size_t)(m0 + lg * 4 + r) * D + nt * 16 + lr] = acc[nt][r];
}

// ---------------- launcher ----------------
extern "C" void kernel_launch(void* const* d_in, const int* in_sizes, int n_in,
                              void* d_out, int out_size, void* d_ws, size_t ws_size,
                              hipStream_t stream) {
    (void)in_sizes; (void)n_in; (void)out_size; (void)ws_size;
    const float* msg = (const float*)d_in[0];
    const float* Wq  = (const float*)d_in[1];
    const float* bq  = (const float*)d_in[2];
    const float* Wk  = (const float*)d_in[3];
    const float* bk  = (const float*)d_in[4];
    const float* Wv  = (const float*)d_in[5];
    const float* bv  = (const float*)d_in[6];
    const float* Wo  = (const float*)d_in[7];
    float* out = (float*)d_out;

    char* p = (char*)d_ws;
    bf16*  Abf  = (bf16*)p;  p += (size_t)M * IN * 2;      // 8 MB
    bf16*  Wt   = (bf16*)p;  p += (size_t)QKV * IN * 2;    // 768 KB
    float* bias = (float*)p; p += (size_t)QKV * 4;         // 6 KB
    bf16*  Wot  = (bf16*)p;  p += (size_t)D * HD * 2;      // 64 KB
    bf16*  Qb   = (bf16*)p;  p += (size_t)Bsz * H * N * D * 2;   // 16 MB
    bf16*  Kb   = (bf16*)p;  p += (size_t)Bsz * H * N * D * 2;   // 16 MB
    bf16*  Vtb  = (bf16*)p;  p += (size_t)Bsz * H * D * N * 2;   // 16 MB
    bf16*  Ctx  = (bf16*)p;  p += (size_t)M * HD * 2;            // 16 MB

    cvt_msg<<<(M * IN / 4) / 256, 256, 0, stream>>>(msg, Abf);
    pack_w<<<(QKV * IN + D * HD + QKV + 255) / 256, 256, 0, stream>>>(
        Wq, Wk, Wv, bq, bk, bv, Wo, Wt, bias, Wot);

    dim3 g1(M / 128, QKV / 128);     // 128 x 12
    qkv_gemm<<<g1, 256, 0, stream>>>(Abf, Wt, bias, Qb, Kb, Vtb);

    dim3 g2(Bsz * H, N / 128);       // 64 x 16 : same-bh blocks land on same XCD
    attn_kernel<<<g2, 256, 0, stream>>>(Qb, Kb, Vtb, Ctx);

    out_gemm<<<M / 64, 256, 0, stream>>>(Ctx, Wot, out);
}

// Round 5
// 294.423 us; speedup vs baseline: 1.9909x; 1.3889x over previous
//
#include <hip/hip_runtime.h>

typedef __bf16 bf16;
typedef __bf16 bf16x4 __attribute__((ext_vector_type(4)));
typedef __bf16 bf16x8 __attribute__((ext_vector_type(8)));
typedef float f32x4 __attribute__((ext_vector_type(4)));

#define SCLOG 0.1803368801111244f   // 0.125 * log2(e)

constexpr int Bsz = 8, N = 2048, IN = 256, H = 8, D = 64;
constexpr int M = Bsz * N;       // 16384 rows
constexpr int HD = H * D;        // 512
constexpr int QKV = 3 * HD;      // 1536

// ---------------- prep kernels ----------------
__global__ void cvt_msg(const float* __restrict__ in, bf16* __restrict__ out) {
    int i = blockIdx.x * blockDim.x + threadIdx.x;   // one float4 per thread
    float4 v = ((const float4*)in)[i];
    bf16x4 o = { (bf16)v.x, (bf16)v.y, (bf16)v.z, (bf16)v.w };
    ((bf16x4*)out)[i] = o;
}

__global__ void pack_w(const float* __restrict__ Wq, const float* __restrict__ Wk,
                       const float* __restrict__ Wv, const float* __restrict__ bq,
                       const float* __restrict__ bk, const float* __restrict__ bv,
                       const float* __restrict__ Wo,
                       bf16* __restrict__ Wt, float* __restrict__ bias,
                       bf16* __restrict__ Wot) {
    int idx = blockIdx.x * 256 + threadIdx.x;
    if (idx < QKV * IN) {                 // Wt[c][k] = W(k, c%512), c-major
        int c = idx / IN, k = idx - c * IN;
        const float* W = (c < HD) ? Wq : (c < 2 * HD ? Wk : Wv);
        Wt[idx] = (bf16)W[k * HD + (c & (HD - 1))];
        return;
    }
    idx -= QKV * IN;
    if (idx < D * HD) {                   // Wot[d][c] = Wo[c][d]
        int d = idx / HD, c = idx - d * HD;
        Wot[idx] = (bf16)Wo[c * D + d];
        return;
    }
    idx -= D * HD;
    if (idx < QKV) {
        bias[idx] = (idx < HD) ? bq[idx] : (idx < 2 * HD ? bk[idx - HD] : bv[idx - 2 * HD]);
    }
}

// ---------------- QKV projection GEMM ----------------
__global__ __launch_bounds__(256) void qkv_gemm(
    const bf16* __restrict__ A, const bf16* __restrict__ Wt,
    const float* __restrict__ bias,
    bf16* __restrict__ Q, bf16* __restrict__ K, bf16* __restrict__ Vt) {
    const int w = threadIdx.x >> 6, lane = threadIdx.x & 63;
    const int lr = lane & 15, lg = lane >> 4;
    const int m0 = blockIdx.x * 128 + w * 32;
    const int c0 = blockIdx.y * 128;

    f32x4 acc[2][8] = {};
    const bf16* ap0 = A + (size_t)(m0 + lr) * IN + lg * 8;
    const bf16* ap1 = A + (size_t)(m0 + 16 + lr) * IN + lg * 8;
    const bf16* bp  = Wt + (size_t)(c0 + lr) * IN + lg * 8;

#pragma unroll
    for (int ks = 0; ks < 8; ++ks) {
        bf16x8 a0 = *(const bf16x8*)(ap0 + ks * 32);
        bf16x8 a1 = *(const bf16x8*)(ap1 + ks * 32);
#pragma unroll
        for (int nt = 0; nt < 8; ++nt) {
            bf16x8 bf = *(const bf16x8*)(bp + (size_t)nt * 16 * IN + ks * 32);
            acc[0][nt] = __builtin_amdgcn_mfma_f32_16x16x32_bf16(a0, bf, acc[0][nt], 0, 0, 0);
            acc[1][nt] = __builtin_amdgcn_mfma_f32_16x16x32_bf16(a1, bf, acc[1][nt], 0, 0, 0);
        }
    }

#pragma unroll
    for (int mt = 0; mt < 2; ++mt) {
        int rowb = m0 + mt * 16 + lg * 4;
#pragma unroll
        for (int nt = 0; nt < 8; ++nt) {
            int col = c0 + nt * 16 + lr;
            float bv = bias[col];
            int which = col >> 9;       // 0=Q 1=K 2=V
            int cc = col & (HD - 1);
            int h = cc >> 6, d = cc & 63;
#pragma unroll
            for (int r = 0; r < 4; ++r) {
                float v = acc[mt][nt][r] + bv;
                int row = rowb + r;
                int b = row >> 11, n = row & (N - 1);
                if (which == 0)      Q[(((size_t)(b * H + h) * N) + n) * D + d] = (bf16)v;
                else if (which == 1) K[(((size_t)(b * H + h) * N) + n) * D + d] = (bf16)v;
                else                 Vt[((size_t)(b * H + h) * D + d) * N + n] = (bf16)v;
            }
        }
    }
}

// ---------------- fused attention v3 ----------------
// 8 waves/block, 256 q-rows/block (32/wave). K,V tiles (64x64 bf16) staged in
// LDS via global_load_lds (16B), double-buffered, XOR-swizzled both sides:
//   LDS[row][cb] = G[row][cb ^ ((row&7)<<4)]  (pre-swizzled global source,
//   linear LDS dest; ds_read applies the same XOR) -> conflict-free b128 reads.
// Swapped QK^T (mfma(K,Q)): lane holds col q = lane&15, rows k.
__device__ __forceinline__ void stage_tile(const bf16* __restrict__ srcRowBase,
                                           size_t rowStride, bf16* ldsBase,
                                           int w, int lane) {
    int r8 = lane >> 3;                       // 0..7: row within wave's 8-row chunk
    int cb = ((lane & 7) ^ r8) << 4;          // pre-swizzled source col (bytes)
    const bf16* g = srcRowBase + (size_t)(w * 8 + r8) * rowStride + (cb >> 1);
    bf16* l = ldsBase + w * 8 * 64;           // wave-uniform; HW adds lane*16
    __builtin_amdgcn_global_load_lds(
        (const __attribute__((address_space(1))) char*)g,
        (__attribute__((address_space(3))) char*)l, 16, 0, 0);
}

__global__ __launch_bounds__(512, 4) void attn_kernel(
    const bf16* __restrict__ Qg, const bf16* __restrict__ Kg,
    const bf16* __restrict__ Vtg, bf16* __restrict__ ctx) {
    __shared__ bf16 Kb[2][64][64];   // 16 KB
    __shared__ bf16 Vb[2][64][64];   // 16 KB  (rows d, cols k)
    __shared__ bf16 P[8][32][64];    // 32 KB, XOR-swizzled rows (128B)
    const int w = threadIdx.x >> 6, lane = threadIdx.x & 63;
    const int lr = lane & 15, lg = lane >> 4;
    const int bh = blockIdx.x;
    const int q0 = blockIdx.y * 256 + w * 32;   // wave's 32 q-rows

    const bf16* Qp = Qg + (size_t)bh * N * D;
    const bf16* Kp = Kg + (size_t)bh * N * D;
    const bf16* Vp = Vtg + (size_t)bh * D * N;

    // Q fragments (B-operand): lane holds Q[q0+qt*16+lr][kd*32+lg*8 ..+8]
    bf16x8 qf[2][2];
#pragma unroll
    for (int qt = 0; qt < 2; ++qt)
#pragma unroll
        for (int kd = 0; kd < 2; ++kd)
            qf[qt][kd] = *(const bf16x8*)(Qp + (size_t)(q0 + qt * 16 + lr) * D + kd * 32 + lg * 8);

    float mrow[2] = { -1e30f, -1e30f };   // running max (raw scores) for q = lr + 16*qt
    float lrow[2] = { 0.f, 0.f };
    f32x4 cacc[2][4] = {};                // rows q = 4*lg + r, cols d = dt*16 + lr

    // prologue: stage tile 0
    stage_tile(Kp, 64, &Kb[0][0][0], w, lane);
    stage_tile(Vp, N,  &Vb[0][0][0], w, lane);
    __syncthreads();
    int cur = 0;

    const int swz = (lr & 7) << 4;        // byte XOR for this lane's frag rows
    char* prow0 = (char*)&P[w][lr][0];    // q-row lr (qt adds 16 rows = 2048B)

    for (int kt = 0; kt < N / 64; ++kt) {
        const int kk0 = kt * 64;
        if (kt + 1 < N / 64) {            // issue next tile's staging early
            stage_tile(Kp + (size_t)(kk0 + 64) * 64, 64, &Kb[cur ^ 1][0][0], w, lane);
            stage_tile(Vp + (kk0 + 64),         N,  &Vb[cur ^ 1][0][0], w, lane);
        }
        // ---- S^T = K Q^T  (raw, unscaled)
        const char* kbase = (const char*)&Kb[cur][0][0];
        f32x4 s[2][4] = {};
#pragma unroll
        for (int nt = 0; nt < 4; ++nt)
#pragma unroll
            for (int kd = 0; kd < 2; ++kd) {
                bf16x8 kf = *(const bf16x8*)(kbase + (nt * 16 + lr) * 128 + ((kd * 64 + lg * 16) ^ swz));
                s[0][nt] = __builtin_amdgcn_mfma_f32_16x16x32_bf16(kf, qf[0][kd], s[0][nt], 0, 0, 0);
                s[1][nt] = __builtin_amdgcn_mfma_f32_16x16x32_bf16(kf, qf[1][kd], s[1][nt], 0, 0, 0);
            }
        // ---- exclude-self mask, only on tiles that touch the diagonal
        if (kk0 < q0 + 32 && q0 < kk0 + 64) {
#pragma unroll
            for (int qt = 0; qt < 2; ++qt) {
                int q = q0 + qt * 16 + lr;
#pragma unroll
                for (int nt = 0; nt < 4; ++nt)
#pragma unroll
                    for (int r = 0; r < 4; ++r)
                        if (kk0 + nt * 16 + lg * 4 + r == q) s[qt][nt][r] = -3e38f;
            }
        }
        // ---- row max (raw): in-reg tree + 2 shuffles; defer-max check
        float rm[2];
        bool need = false;
#pragma unroll
        for (int qt = 0; qt < 2; ++qt) {
            float v = s[qt][0][0];
#pragma unroll
            for (int nt = 0; nt < 4; ++nt)
#pragma unroll
                for (int r = 0; r < 4; ++r) v = fmaxf(v, s[qt][nt][r]);
            v = fmaxf(v, __shfl_xor(v, 16));
            v = fmaxf(v, __shfl_xor(v, 32));
            rm[qt] = v;
            need = need || (v > mrow[qt] + 64.f);   // 64 raw = 8 post-scale
        }
        if (__any(need)) {
#pragma unroll
            for (int qt = 0; qt < 2; ++qt) {
                float mn = fmaxf(mrow[qt], rm[qt]);
                float f = exp2f((mrow[qt] - mn) * SCLOG);
                mrow[qt] = mn;
                lrow[qt] *= f;
#pragma unroll
                for (int r = 0; r < 4; ++r) {
                    float fr = __shfl(f, lg * 4 + r);
#pragma unroll
                    for (int dt = 0; dt < 4; ++dt) cacc[qt][dt][r] *= fr;
                }
            }
        }
        // ---- P = exp2((s - m)*SCLOG), pack b64 to LDS (swizzled), row sums
#pragma unroll
        for (int qt = 0; qt < 2; ++qt) {
            float mc = mrow[qt] * SCLOG;
            float ps = 0.f;
            char* prow = prow0 + qt * 2048;
#pragma unroll
            for (int nt = 0; nt < 4; ++nt) {
                float p0 = exp2f(__builtin_fmaf(s[qt][nt][0], SCLOG, -mc));
                float p1 = exp2f(__builtin_fmaf(s[qt][nt][1], SCLOG, -mc));
                float p2 = exp2f(__builtin_fmaf(s[qt][nt][2], SCLOG, -mc));
                float p3 = exp2f(__builtin_fmaf(s[qt][nt][3], SCLOG, -mc));
                ps += (p0 + p1) + (p2 + p3);
                bf16x4 pk = { (bf16)p0, (bf16)p1, (bf16)p2, (bf16)p3 };
                *(bf16x4*)(prow + ((nt * 32 + lg * 8) ^ swz)) = pk;
            }
            ps += __shfl_xor(ps, 16);
            ps += __shfl_xor(ps, 32);
            lrow[qt] += ps;
        }
        // ---- ctx += P V   (A-frag from P, B-frag from staged Vb)
        const char* vbase = (const char*)&Vb[cur][0][0];
#pragma unroll
        for (int ks = 0; ks < 2; ++ks) {
            bf16x8 pa[2];
#pragma unroll
            for (int qt = 0; qt < 2; ++qt)
                pa[qt] = *(const bf16x8*)(prow0 + qt * 2048 + ((ks * 64 + lg * 16) ^ swz));
#pragma unroll
            for (int dt = 0; dt < 4; ++dt) {
                bf16x8 vf = *(const bf16x8*)(vbase + (dt * 16 + lr) * 128 + ((ks * 64 + lg * 16) ^ swz));
                cacc[0][dt] = __builtin_amdgcn_mfma_f32_16x16x32_bf16(pa[0], vf, cacc[0][dt], 0, 0, 0);
                cacc[1][dt] = __builtin_amdgcn_mfma_f32_16x16x32_bf16(pa[1], vf, cacc[1][dt], 0, 0, 0);
            }
        }
        __syncthreads();                  // drains staging vmcnt + sync readers
        cur ^= 1;
    }
    // ---- epilogue: ctx[b][n=q][h*64+d];  cacc rows are q = 4*lg + r
    const int b = bh >> 3, h = bh & 7;
#pragma unroll
    for (int qt = 0; qt < 2; ++qt) {
        float ool = 1.0f / lrow[qt];
#pragma unroll
        for (int r = 0; r < 4; ++r) {
            float oolr = __shfl(ool, lg * 4 + r);
            int q = q0 + qt * 16 + lg * 4 + r;
#pragma unroll
            for (int dt = 0; dt < 4; ++dt)
                ctx[((size_t)(b * N + q)) * HD + h * 64 + dt * 16 + lr] =
                    (bf16)(cacc[qt][dt][r] * oolr);
        }
    }
}

// ---------------- output projection ----------------
__global__ __launch_bounds__(256) void out_gemm(
    const bf16* __restrict__ ctx, const bf16* __restrict__ Wot,
    float* __restrict__ out) {
    const int w = threadIdx.x >> 6, lane = threadIdx.x & 63;
    const int lr = lane & 15, lg = lane >> 4;
    const int m0 = blockIdx.x * 64 + w * 16;
    f32x4 acc[4] = {};
#pragma unroll
    for (int ks = 0; ks < 16; ++ks) {
        bf16x8 af = *(const bf16x8*)(ctx + (size_t)(m0 + lr) * HD + ks * 32 + lg * 8);
#pragma unroll
        for (int nt = 0; nt < 4; ++nt) {
            bf16x8 wf = *(const bf16x8*)(Wot + (size_t)(nt * 16 + lr) * HD + ks * 32 + lg * 8);
            acc[nt] = __builtin_amdgcn_mfma_f32_16x16x32_bf16(af, wf, acc[nt], 0, 0, 0);
        }
    }
#pragma unroll
    for (int nt = 0; nt < 4; ++nt)
#pragma unroll
        for (int r = 0; r < 4; ++r)
            out[(size_t)(m0 + lg * 4 + r) * D + nt * 16 + lr] = acc[nt][r];
}

// ---------------- launcher ----------------
extern "C" void kernel_launch(void* const* d_in, const int* in_sizes, int n_in,
                              void* d_out, int out_size, void* d_ws, size_t ws_size,
                              hipStream_t stream) {
    (void)in_sizes; (void)n_in; (void)out_size; (void)ws_size;
    const float* msg = (const float*)d_in[0];
    const float* Wq  = (const float*)d_in[1];
    const float* bq  = (const float*)d_in[2];
    const float* Wk  = (const float*)d_in[3];
    const float* bk  = (const float*)d_in[4];
    const float* Wv  = (const float*)d_in[5];
    const float* bv  = (const float*)d_in[6];
    const float* Wo  = (const float*)d_in[7];
    float* out = (float*)d_out;

    char* p = (char*)d_ws;
    bf16*  Abf  = (bf16*)p;  p += (size_t)M * IN * 2;      // 8 MB
    bf16*  Wt   = (bf16*)p;  p += (size_t)QKV * IN * 2;    // 768 KB
    float* bias = (float*)p; p += (size_t)QKV * 4;         // 6 KB
    bf16*  Wot  = (bf16*)p;  p += (size_t)D * HD * 2;      // 64 KB
    bf16*  Qb   = (bf16*)p;  p += (size_t)Bsz * H * N * D * 2;   // 16 MB
    bf16*  Kb   = (bf16*)p;  p += (size_t)Bsz * H * N * D * 2;   // 16 MB
    bf16*  Vtb  = (bf16*)p;  p += (size_t)Bsz * H * D * N * 2;   // 16 MB
    bf16*  Ctx  = (bf16*)p;  p += (size_t)M * HD * 2;            // 16 MB

    cvt_msg<<<(M * IN / 4) / 256, 256, 0, stream>>>(msg, Abf);
    pack_w<<<(QKV * IN + D * HD + QKV + 255) / 256, 256, 0, stream>>>(
        Wq, Wk, Wv, bq, bk, bv, Wo, Wt, bias, Wot);

    dim3 g1(M / 128, QKV / 128);     // 128 x 12
    qkv_gemm<<<g1, 256, 0, stream>>>(Abf, Wt, bias, Qb, Kb, Vtb);

    dim3 g2(Bsz * H, N / 256);       // 64 x 8 : 512 blocks, 2/CU
    attn_kernel<<<g2, 512, 0, stream>>>(Qb, Kb, Vtb, Ctx);

    out_gemm<<<M / 64, 256, 0, stream>>>(Ctx, Wot, out);
}

// Round 10
// 271.425 us; speedup vs baseline: 2.1596x; 1.0847x over previous
//
#include <hip/hip_runtime.h>

typedef __bf16 bf16;
typedef __bf16 bf16x4 __attribute__((ext_vector_type(4)));
typedef __bf16 bf16x8 __attribute__((ext_vector_type(8)));
typedef float f32x4 __attribute__((ext_vector_type(4)));

#define SCLOG 0.1803368801111244f   // 0.125 * log2(e)

constexpr int Bsz = 8, N = 2048, IN = 256, H = 8, D = 64;
constexpr int M = Bsz * N;       // 16384 rows
constexpr int HD = H * D;        // 512
constexpr int QKV = 3 * HD;      // 1536

// ---------------- prep kernels ----------------
__global__ void cvt_msg(const float* __restrict__ in, bf16* __restrict__ out) {
    int i = blockIdx.x * blockDim.x + threadIdx.x;   // one float4 per thread
    float4 v = ((const float4*)in)[i];
    bf16x4 o = { (bf16)v.x, (bf16)v.y, (bf16)v.z, (bf16)v.w };
    ((bf16x4*)out)[i] = o;
}

// Tiled transposes: Wq/Wk/Wv (256x512) -> Wt rows, Wo (512x64) -> Wot, + bias.
__global__ __launch_bounds__(256) void pack_w(
    const float* __restrict__ Wq, const float* __restrict__ Wk,
    const float* __restrict__ Wv, const float* __restrict__ bq,
    const float* __restrict__ bk, const float* __restrict__ bv,
    const float* __restrict__ Wo,
    bf16* __restrict__ Wt, float* __restrict__ bias, bf16* __restrict__ Wot) {
    __shared__ float Tt[32][33];
    const int tid = blockIdx.x;
    const int tx = threadIdx.x & 31, ty = threadIdx.x >> 5;   // 32 x 8
    if (tid < 384) {                       // 128 tiles per W (8 k-tiles x 16 c-tiles)
        int wsel = tid >> 7, t = tid & 127;
        int k0 = (t >> 4) * 32, cl0 = (t & 15) * 32;
        const float* W = wsel == 0 ? Wq : (wsel == 1 ? Wk : Wv);
#pragma unroll
        for (int i = 0; i < 4; ++i)
            Tt[ty + i * 8][tx] = W[(size_t)(k0 + ty + i * 8) * HD + cl0 + tx];
        __syncthreads();
#pragma unroll
        for (int i = 0; i < 4; ++i)
            Wt[(size_t)(wsel * HD + cl0 + ty + i * 8) * IN + k0 + tx] =
                (bf16)Tt[tx][ty + i * 8];
    } else if (tid < 416) {                // Wo 512x64: 16 x 2 tiles
        int t = tid - 384;
        int r0 = (t >> 1) * 32, c0 = (t & 1) * 32;
#pragma unroll
        for (int i = 0; i < 4; ++i)
            Tt[ty + i * 8][tx] = Wo[(size_t)(r0 + ty + i * 8) * D + c0 + tx];
        __syncthreads();
#pragma unroll
        for (int i = 0; i < 4; ++i)
            Wot[(size_t)(c0 + ty + i * 8) * HD + r0 + tx] = (bf16)Tt[tx][ty + i * 8];
    } else {                               // bias concat
        for (int v = threadIdx.x; v < QKV; v += 256)
            bias[v] = v < HD ? bq[v] : (v < 2 * HD ? bk[v - HD] : bv[v - 2 * HD]);
    }
}

// ---------------- QKV projection GEMM ----------------
// C[m][c] = A[m][:].Wt[c][:] + bias[c].  Q,K scattered [B,H,N,D] directly;
// V blocks transpose through LDS -> coalesced Vt ([B,H,D,N]) stores.
__global__ __launch_bounds__(256) void qkv_gemm(
    const bf16* __restrict__ A, const bf16* __restrict__ Wt,
    const float* __restrict__ bias,
    bf16* __restrict__ Q, bf16* __restrict__ K, bf16* __restrict__ Vt) {
    __shared__ bf16 Tv[128][136];   // V-transpose staging; 272B stride: b64/b128 aligned
    const int w = threadIdx.x >> 6, lane = threadIdx.x & 63;
    const int lr = lane & 15, lg = lane >> 4;
    const int mblk = blockIdx.x * 128;
    const int m0 = mblk + w * 32;
    const int c0 = blockIdx.y * 128;

    f32x4 acc[2][8] = {};
    const bf16* ap0 = A + (size_t)(m0 + lr) * IN + lg * 8;
    const bf16* ap1 = A + (size_t)(m0 + 16 + lr) * IN + lg * 8;
    const bf16* bp  = Wt + (size_t)(c0 + lr) * IN + lg * 8;

#pragma unroll
    for (int ks = 0; ks < 8; ++ks) {
        bf16x8 a0 = *(const bf16x8*)(ap0 + ks * 32);
        bf16x8 a1 = *(const bf16x8*)(ap1 + ks * 32);
#pragma unroll
        for (int nt = 0; nt < 8; ++nt) {
            bf16x8 bf = *(const bf16x8*)(bp + (size_t)nt * 16 * IN + ks * 32);
            acc[0][nt] = __builtin_amdgcn_mfma_f32_16x16x32_bf16(a0, bf, acc[0][nt], 0, 0, 0);
            acc[1][nt] = __builtin_amdgcn_mfma_f32_16x16x32_bf16(a1, bf, acc[1][nt], 0, 0, 0);
        }
    }

    if (c0 < 2 * HD) {
        // ---- Q/K path (block-uniform target)
        bf16* dst = (c0 < HD) ? Q : K;
#pragma unroll
        for (int mt = 0; mt < 2; ++mt) {
            int rowb = m0 + mt * 16 + lg * 4;
#pragma unroll
            for (int nt = 0; nt < 8; ++nt) {
                int cc = (c0 + nt * 16 + lr) & (HD - 1);
                float bv = bias[c0 + nt * 16 + lr];
                int h = cc >> 6, d = cc & 63;
#pragma unroll
                for (int r = 0; r < 4; ++r) {
                    int row = rowb + r;
                    int b = row >> 11, n = row & (N - 1);
                    dst[(((size_t)(b * H + h) * N) + n) * D + d] =
                        (bf16)(acc[mt][nt][r] + bv);
                }
            }
        }
    } else {
        // ---- V path: acc -> LDS [c_local][m_local], then coalesced Vt rows
#pragma unroll
        for (int mt = 0; mt < 2; ++mt) {
            int mb = w * 32 + mt * 16 + lg * 4;
#pragma unroll
            for (int nt = 0; nt < 8; ++nt) {
                int cl = nt * 16 + lr;
                float bv = bias[c0 + cl];
                bf16x4 pk = { (bf16)(acc[mt][nt][0] + bv), (bf16)(acc[mt][nt][1] + bv),
                              (bf16)(acc[mt][nt][2] + bv), (bf16)(acc[mt][nt][3] + bv) };
                *(bf16x4*)&Tv[cl][mb] = pk;
            }
        }
        __syncthreads();
        const int cc0 = c0 - 2 * HD;
        const int b = mblk >> 11;
        const int nb = mblk & (N - 1);   // n-offset within the sequence (bug fix)
        const int j = threadIdx.x & 15;
#pragma unroll
        for (int pass = 0; pass < 8; ++pass) {
            int cl = pass * 16 + (threadIdx.x >> 4);
            int cc = cc0 + cl, h = cc >> 6, d = cc & 63;
            bf16x8 vv = *(const bf16x8*)&Tv[cl][j * 8];
            *(bf16x8*)(Vt + ((size_t)(b * H + h) * D + d) * N + nb + j * 8) = vv;
        }
    }
}

// ---------------- fused attention v3 (unchanged from round 5) ----------------
__device__ __forceinline__ void stage_tile(const bf16* __restrict__ srcRowBase,
                                           size_t rowStride, bf16* ldsBase,
                                           int w, int lane) {
    int r8 = lane >> 3;                       // 0..7: row within wave's 8-row chunk
    int cb = ((lane & 7) ^ r8) << 4;          // pre-swizzled source col (bytes)
    const bf16* g = srcRowBase + (size_t)(w * 8 + r8) * rowStride + (cb >> 1);
    bf16* l = ldsBase + w * 8 * 64;           // wave-uniform; HW adds lane*16
    __builtin_amdgcn_global_load_lds(
        (const __attribute__((address_space(1))) char*)g,
        (__attribute__((address_space(3))) char*)l, 16, 0, 0);
}

__global__ __launch_bounds__(512, 4) void attn_kernel(
    const bf16* __restrict__ Qg, const bf16* __restrict__ Kg,
    const bf16* __restrict__ Vtg, bf16* __restrict__ ctx) {
    __shared__ bf16 Kb[2][64][64];   // 16 KB
    __shared__ bf16 Vb[2][64][64];   // 16 KB  (rows d, cols k)
    __shared__ bf16 P[8][32][64];    // 32 KB, XOR-swizzled rows (128B)
    const int w = threadIdx.x >> 6, lane = threadIdx.x & 63;
    const int lr = lane & 15, lg = lane >> 4;
    const int bh = blockIdx.x;
    const int q0 = blockIdx.y * 256 + w * 32;   // wave's 32 q-rows

    const bf16* Qp = Qg + (size_t)bh * N * D;
    const bf16* Kp = Kg + (size_t)bh * N * D;
    const bf16* Vp = Vtg + (size_t)bh * D * N;

    bf16x8 qf[2][2];
#pragma unroll
    for (int qt = 0; qt < 2; ++qt)
#pragma unroll
        for (int kd = 0; kd < 2; ++kd)
            qf[qt][kd] = *(const bf16x8*)(Qp + (size_t)(q0 + qt * 16 + lr) * D + kd * 32 + lg * 8);

    float mrow[2] = { -1e30f, -1e30f };
    float lrow[2] = { 0.f, 0.f };
    f32x4 cacc[2][4] = {};

    stage_tile(Kp, 64, &Kb[0][0][0], w, lane);
    stage_tile(Vp, N,  &Vb[0][0][0], w, lane);
    __syncthreads();
    int cur = 0;

    const int swz = (lr & 7) << 4;
    char* prow0 = (char*)&P[w][lr][0];

    for (int kt = 0; kt < N / 64; ++kt) {
        const int kk0 = kt * 64;
        if (kt + 1 < N / 64) {
            stage_tile(Kp + (size_t)(kk0 + 64) * 64, 64, &Kb[cur ^ 1][0][0], w, lane);
            stage_tile(Vp + (kk0 + 64),         N,  &Vb[cur ^ 1][0][0], w, lane);
        }
        const char* kbase = (const char*)&Kb[cur][0][0];
        f32x4 s[2][4] = {};
#pragma unroll
        for (int nt = 0; nt < 4; ++nt)
#pragma unroll
            for (int kd = 0; kd < 2; ++kd) {
                bf16x8 kf = *(const bf16x8*)(kbase + (nt * 16 + lr) * 128 + ((kd * 64 + lg * 16) ^ swz));
                s[0][nt] = __builtin_amdgcn_mfma_f32_16x16x32_bf16(kf, qf[0][kd], s[0][nt], 0, 0, 0);
                s[1][nt] = __builtin_amdgcn_mfma_f32_16x16x32_bf16(kf, qf[1][kd], s[1][nt], 0, 0, 0);
            }
        if (kk0 < q0 + 32 && q0 < kk0 + 64) {
#pragma unroll
            for (int qt = 0; qt < 2; ++qt) {
                int q = q0 + qt * 16 + lr;
#pragma unroll
                for (int nt = 0; nt < 4; ++nt)
#pragma unroll
                    for (int r = 0; r < 4; ++r)
                        if (kk0 + nt * 16 + lg * 4 + r == q) s[qt][nt][r] = -3e38f;
            }
        }
        float rm[2];
        bool need = false;
#pragma unroll
        for (int qt = 0; qt < 2; ++qt) {
            float v = s[qt][0][0];
#pragma unroll
            for (int nt = 0; nt < 4; ++nt)
#pragma unroll
                for (int r = 0; r < 4; ++r) v = fmaxf(v, s[qt][nt][r]);
            v = fmaxf(v, __shfl_xor(v, 16));
            v = fmaxf(v, __shfl_xor(v, 32));
            rm[qt] = v;
            need = need || (v > mrow[qt] + 64.f);
        }
        if (__any(need)) {
#pragma unroll
            for (int qt = 0; qt < 2; ++qt) {
                float mn = fmaxf(mrow[qt], rm[qt]);
                float f = exp2f((mrow[qt] - mn) * SCLOG);
                mrow[qt] = mn;
                lrow[qt] *= f;
#pragma unroll
                for (int r = 0; r < 4; ++r) {
                    float fr = __shfl(f, lg * 4 + r);
#pragma unroll
                    for (int dt = 0; dt < 4; ++dt) cacc[qt][dt][r] *= fr;
                }
            }
        }
#pragma unroll
        for (int qt = 0; qt < 2; ++qt) {
            float mc = mrow[qt] * SCLOG;
            float ps = 0.f;
            char* prow = prow0 + qt * 2048;
#pragma unroll
            for (int nt = 0; nt < 4; ++nt) {
                float p0 = exp2f(__builtin_fmaf(s[qt][nt][0], SCLOG, -mc));
                float p1 = exp2f(__builtin_fmaf(s[qt][nt][1], SCLOG, -mc));
                float p2 = exp2f(__builtin_fmaf(s[qt][nt][2], SCLOG, -mc));
                float p3 = exp2f(__builtin_fmaf(s[qt][nt][3], SCLOG, -mc));
                ps += (p0 + p1) + (p2 + p3);
                bf16x4 pk = { (bf16)p0, (bf16)p1, (bf16)p2, (bf16)p3 };
                *(bf16x4*)(prow + ((nt * 32 + lg * 8) ^ swz)) = pk;
            }
            ps += __shfl_xor(ps, 16);
            ps += __shfl_xor(ps, 32);
            lrow[qt] += ps;
        }
        const char* vbase = (const char*)&Vb[cur][0][0];
#pragma unroll
        for (int ks = 0; ks < 2; ++ks) {
            bf16x8 pa[2];
#pragma unroll
            for (int qt = 0; qt < 2; ++qt)
                pa[qt] = *(const bf16x8*)(prow0 + qt * 2048 + ((ks * 64 + lg * 16) ^ swz));
#pragma unroll
            for (int dt = 0; dt < 4; ++dt) {
                bf16x8 vf = *(const bf16x8*)(vbase + (dt * 16 + lr) * 128 + ((ks * 64 + lg * 16) ^ swz));
                cacc[0][dt] = __builtin_amdgcn_mfma_f32_16x16x32_bf16(pa[0], vf, cacc[0][dt], 0, 0, 0);
                cacc[1][dt] = __builtin_amdgcn_mfma_f32_16x16x32_bf16(pa[1], vf, cacc[1][dt], 0, 0, 0);
            }
        }
        __syncthreads();
        cur ^= 1;
    }
    const int b = bh >> 3, h = bh & 7;
#pragma unroll
    for (int qt = 0; qt < 2; ++qt) {
        float ool = 1.0f / lrow[qt];
#pragma unroll
        for (int r = 0; r < 4; ++r) {
            float oolr = __shfl(ool, lg * 4 + r);
            int q = q0 + qt * 16 + lg * 4 + r;
#pragma unroll
            for (int dt = 0; dt < 4; ++dt)
                ctx[((size_t)(b * N + q)) * HD + h * 64 + dt * 16 + lr] =
                    (bf16)(cacc[qt][dt][r] * oolr);
        }
    }
}

// ---------------- output projection ----------------
__global__ __launch_bounds__(256) void out_gemm(
    const bf16* __restrict__ ctx, const bf16* __restrict__ Wot,
    float* __restrict__ out) {
    const int w = threadIdx.x >> 6, lane = threadIdx.x & 63;
    const int lr = lane & 15, lg = lane >> 4;
    const int m0 = blockIdx.x * 64 + w * 16;
    f32x4 acc[4] = {};
#pragma unroll
    for (int ks = 0; ks < 16; ++ks) {
        bf16x8 af = *(const bf16x8*)(ctx + (size_t)(m0 + lr) * HD + ks * 32 + lg * 8);
#pragma unroll
        for (int nt = 0; nt < 4; ++nt) {
            bf16x8 wf = *(const bf16x8*)(Wot + (size_t)(nt * 16 + lr) * HD + ks * 32 + lg * 8);
            acc[nt] = __builtin_amdgcn_mfma_f32_16x16x32_bf16(af, wf, acc[nt], 0, 0, 0);
        }
    }
#pragma unroll
    for (int nt = 0; nt < 4; ++nt)
#pragma unroll
        for (int r = 0; r < 4; ++r)
            out[(size_t)(m0 + lg * 4 + r) * D + nt * 16 + lr] = acc[nt][r];
}

// ---------------- launcher ----------------
extern "C" void kernel_launch(void* const* d_in, const int* in_sizes, int n_in,
                              void* d_out, int out_size, void* d_ws, size_t ws_size,
                              hipStream_t stream) {
    (void)in_sizes; (void)n_in; (void)out_size; (void)ws_size;
    const float* msg = (const float*)d_in[0];
    const float* Wq  = (const float*)d_in[1];
    const float* bq  = (const float*)d_in[2];
    const float* Wk  = (const float*)d_in[3];
    const float* bk  = (const float*)d_in[4];
    const float* Wv  = (const float*)d_in[5];
    const float* bv  = (const float*)d_in[6];
    const float* Wo  = (const float*)d_in[7];
    float* out = (float*)d_out;

    char* p = (char*)d_ws;
    bf16*  Abf  = (bf16*)p;  p += (size_t)M * IN * 2;      // 8 MB
    bf16*  Wt   = (bf16*)p;  p += (size_t)QKV * IN * 2;    // 768 KB
    float* bias = (float*)p; p += (size_t)QKV * 4;         // 6 KB
    bf16*  Wot  = (bf16*)p;  p += (size_t)D * HD * 2;      // 64 KB
    bf16*  Qb   = (bf16*)p;  p += (size_t)Bsz * H * N * D * 2;   // 16 MB
    bf16*  Kb   = (bf16*)p;  p += (size_t)Bsz * H * N * D * 2;   // 16 MB
    bf16*  Vtb  = (bf16*)p;  p += (size_t)Bsz * H * D * N * 2;   // 16 MB
    bf16*  Ctx  = (bf16*)p;  p += (size_t)M * HD * 2;            // 16 MB

    cvt_msg<<<(M * IN / 4) / 256, 256, 0, stream>>>(msg, Abf);
    pack_w<<<417, 256, 0, stream>>>(Wq, Wk, Wv, bq, bk, bv, Wo, Wt, bias, Wot);

    dim3 g1(M / 128, QKV / 128);     // 128 x 12
    qkv_gemm<<<g1, 256, 0, stream>>>(Abf, Wt, bias, Qb, Kb, Vtb);

    dim3 g2(Bsz * H, N / 256);       // 64 x 8 : 512 blocks, 2/CU
    attn_kernel<<<g2, 512, 0, stream>>>(Qb, Kb, Vtb, Ctx);

    out_gemm<<<M / 64, 256, 0, stream>>>(Ctx, Wot, out);
}

// Round 11
// 226.533 us; speedup vs baseline: 2.5875x; 1.1982x over previous
//
#include <hip/hip_runtime.h>

typedef __bf16 bf16;
typedef __bf16 bf16x4 __attribute__((ext_vector_type(4)));
typedef __bf16 bf16x8 __attribute__((ext_vector_type(8)));
typedef float f32x4 __attribute__((ext_vector_type(4)));

#define SCLOG 0.1803368801111244f   // 0.125 * log2(e)

constexpr int Bsz = 8, N = 2048, IN = 256, H = 8, D = 64;
constexpr int M = Bsz * N;       // 16384 rows
constexpr int HD = H * D;        // 512
constexpr int QKV = 3 * HD;      // 1536

// Stage 8 rows x 64 cols (bf16) into LDS via global_load_lds, 16B/lane.
// LDS dest linear; source column pre-swizzled (XOR r8) so swizzled ds_reads
// land conflict-free (both-sides rule).
__device__ __forceinline__ void stage8(const bf16* __restrict__ src, size_t stride,
                                       bf16* ldsBase, int row0, int lane) {
    int r8 = lane >> 3;
    int cb = ((lane & 7) ^ r8) << 4;
    const bf16* g = src + (size_t)(row0 + r8) * stride + (cb >> 1);
    bf16* l = ldsBase + row0 * 64;
    __builtin_amdgcn_global_load_lds(
        (const __attribute__((address_space(1))) char*)g,
        (__attribute__((address_space(3))) char*)l, 16, 0, 0);
}

// ---------------- prep kernels ----------------
__global__ void cvt_msg(const float* __restrict__ in, bf16* __restrict__ out) {
    int i = blockIdx.x * blockDim.x + threadIdx.x;   // one float4 per thread
    float4 v = ((const float4*)in)[i];
    bf16x4 o = { (bf16)v.x, (bf16)v.y, (bf16)v.z, (bf16)v.w };
    ((bf16x4*)out)[i] = o;
}

// Tiled transposes: Wq/Wk/Wv (256x512) -> Wt rows, Wo (512x64) -> Wot, + bias.
__global__ __launch_bounds__(256) void pack_w(
    const float* __restrict__ Wq, const float* __restrict__ Wk,
    const float* __restrict__ Wv, const float* __restrict__ bq,
    const float* __restrict__ bk, const float* __restrict__ bv,
    const float* __restrict__ Wo,
    bf16* __restrict__ Wt, float* __restrict__ bias, bf16* __restrict__ Wot) {
    __shared__ float Tt[32][33];
    const int tid = blockIdx.x;
    const int tx = threadIdx.x & 31, ty = threadIdx.x >> 5;   // 32 x 8
    if (tid < 384) {                       // 128 tiles per W (8 k-tiles x 16 c-tiles)
        int wsel = tid >> 7, t = tid & 127;
        int k0 = (t >> 4) * 32, cl0 = (t & 15) * 32;
        const float* W = wsel == 0 ? Wq : (wsel == 1 ? Wk : Wv);
#pragma unroll
        for (int i = 0; i < 4; ++i)
            Tt[ty + i * 8][tx] = W[(size_t)(k0 + ty + i * 8) * HD + cl0 + tx];
        __syncthreads();
#pragma unroll
        for (int i = 0; i < 4; ++i)
            Wt[(size_t)(wsel * HD + cl0 + ty + i * 8) * IN + k0 + tx] =
                (bf16)Tt[tx][ty + i * 8];
    } else if (tid < 416) {                // Wo 512x64: 16 x 2 tiles
        int t = tid - 384;
        int r0 = (t >> 1) * 32, c0 = (t & 1) * 32;
#pragma unroll
        for (int i = 0; i < 4; ++i)
            Tt[ty + i * 8][tx] = Wo[(size_t)(r0 + ty + i * 8) * D + c0 + tx];
        __syncthreads();
#pragma unroll
        for (int i = 0; i < 4; ++i)
            Wot[(size_t)(c0 + ty + i * 8) * HD + r0 + tx] = (bf16)Tt[tx][ty + i * 8];
    } else {                               // bias concat
        for (int v = threadIdx.x; v < QKV; v += 256)
            bias[v] = v < HD ? bq[v] : (v < 2 * HD ? bk[v - HD] : bv[v - 2 * HD]);
    }
}

// ---------------- QKV projection GEMM (LDS-staged, double-buffered) --------
// C[m][c] = A[m][:].Wt[c][:] + bias[c].  BK=64, 4 K-steps, global_load_lds.
// Q,K scattered [B,H,N,D]; V transposed through LDS -> coalesced Vt stores.
__global__ __launch_bounds__(256) void qkv_gemm(
    const bf16* __restrict__ A, const bf16* __restrict__ Wt,
    const float* __restrict__ bias,
    bf16* __restrict__ Q, bf16* __restrict__ K, bf16* __restrict__ Vt) {
    __shared__ __align__(16) char smem[65536];  // [2][As 16K|Bs 16K]; epilogue Tv alias
    const int w = threadIdx.x >> 6, lane = threadIdx.x & 63;
    const int lr = lane & 15, lg = lane >> 4;
    const int mblk = blockIdx.x * 128;
    const int m0 = mblk + w * 32;
    const int c0 = blockIdx.y * 128;
    const int swz = (lr & 7) << 4;

    // stage A[128][kk..kk+64] and Wt[c0..+128][kk..kk+64] into buffer `buf`
    auto stage_step = [&](int buf, int kk) {
        bf16* as_ = (bf16*)(smem + buf * 32768);
        bf16* bs_ = (bf16*)(smem + buf * 32768 + 16384);
#pragma unroll
        for (int j = 0; j < 4; ++j) {
            stage8(A + (size_t)mblk * IN + kk, IN, as_, w * 32 + j * 8, lane);
            stage8(Wt + (size_t)c0 * IN + kk, IN, bs_, w * 32 + j * 8, lane);
        }
    };

    f32x4 acc[2][8] = {};
    stage_step(0, 0);
    __syncthreads();
    int cur = 0;

    for (int kstep = 0; kstep < 4; ++kstep) {
        if (kstep < 3) stage_step(cur ^ 1, (kstep + 1) * 64);
        const char* abase = smem + cur * 32768;
        const char* bbase = abase + 16384;
        const char* arow = abase + (w * 32) * 128;
#pragma unroll
        for (int ks = 0; ks < 2; ++ks) {
            bf16x8 a0 = *(const bf16x8*)(arow + lr * 128 + ((ks * 64 + lg * 16) ^ swz));
            bf16x8 a1 = *(const bf16x8*)(arow + (16 + lr) * 128 + ((ks * 64 + lg * 16) ^ swz));
#pragma unroll
            for (int nt = 0; nt < 8; ++nt) {
                bf16x8 bf = *(const bf16x8*)(bbase + (nt * 16 + lr) * 128 + ((ks * 64 + lg * 16) ^ swz));
                acc[0][nt] = __builtin_amdgcn_mfma_f32_16x16x32_bf16(a0, bf, acc[0][nt], 0, 0, 0);
                acc[1][nt] = __builtin_amdgcn_mfma_f32_16x16x32_bf16(a1, bf, acc[1][nt], 0, 0, 0);
            }
        }
        __syncthreads();
        cur ^= 1;
    }

    if (c0 < 2 * HD) {
        // ---- Q/K path (block-uniform target)
        bf16* dst = (c0 < HD) ? Q : K;
#pragma unroll
        for (int mt = 0; mt < 2; ++mt) {
            int rowb = m0 + mt * 16 + lg * 4;
#pragma unroll
            for (int nt = 0; nt < 8; ++nt) {
                int cc = (c0 + nt * 16 + lr) & (HD - 1);
                float bv = bias[c0 + nt * 16 + lr];
                int h = cc >> 6, d = cc & 63;
#pragma unroll
                for (int r = 0; r < 4; ++r) {
                    int row = rowb + r;
                    int b = row >> 11, n = row & (N - 1);
                    dst[(((size_t)(b * H + h) * N) + n) * D + d] =
                        (bf16)(acc[mt][nt][r] + bv);
                }
            }
        }
    } else {
        // ---- V path: acc -> LDS [c_local][m_local] (alias smem), coalesced Vt rows
        bf16 (*Tv)[136] = (bf16(*)[136])smem;   // 272B stride: b64/b128 aligned
#pragma unroll
        for (int mt = 0; mt < 2; ++mt) {
            int mb = w * 32 + mt * 16 + lg * 4;
#pragma unroll
            for (int nt = 0; nt < 8; ++nt) {
                int cl = nt * 16 + lr;
                float bv = bias[c0 + cl];
                bf16x4 pk = { (bf16)(acc[mt][nt][0] + bv), (bf16)(acc[mt][nt][1] + bv),
                              (bf16)(acc[mt][nt][2] + bv), (bf16)(acc[mt][nt][3] + bv) };
                *(bf16x4*)&Tv[cl][mb] = pk;
            }
        }
        __syncthreads();
        const int cc0 = c0 - 2 * HD;
        const int b = mblk >> 11;
        const int nb = mblk & (N - 1);   // n-offset within the sequence
        const int j = threadIdx.x & 15;
#pragma unroll
        for (int pass = 0; pass < 8; ++pass) {
            int cl = pass * 16 + (threadIdx.x >> 4);
            int cc = cc0 + cl, h = cc >> 6, d = cc & 63;
            bf16x8 vv = *(const bf16x8*)&Tv[cl][j * 8];
            *(bf16x8*)(Vt + ((size_t)(b * H + h) * D + d) * N + nb + j * 8) = vv;
        }
    }
}

// ---------------- fused attention v4 ----------------
// v3 + row-sum via MFMA ones-trick: lrow kept in cacc layout (q = 4*lg + r),
// updated by 4 extra MFMAs/kt against a ones B-fragment (replaces 32 VALU
// adds + 4 shuffles on the critical VALU path).
__global__ __launch_bounds__(512, 4) void attn_kernel(
    const bf16* __restrict__ Qg, const bf16* __restrict__ Kg,
    const bf16* __restrict__ Vtg, bf16* __restrict__ ctx) {
    __shared__ bf16 Kb[2][64][64];   // 16 KB
    __shared__ bf16 Vb[2][64][64];   // 16 KB  (rows d, cols k)
    __shared__ bf16 P[8][32][64];    // 32 KB, XOR-swizzled rows (128B)
    const int w = threadIdx.x >> 6, lane = threadIdx.x & 63;
    const int lr = lane & 15, lg = lane >> 4;
    const int bh = blockIdx.x;
    const int q0 = blockIdx.y * 256 + w * 32;   // wave's 32 q-rows

    const bf16* Qp = Qg + (size_t)bh * N * D;
    const bf16* Kp = Kg + (size_t)bh * N * D;
    const bf16* Vp = Vtg + (size_t)bh * D * N;

    bf16x8 qf[2][2];
#pragma unroll
    for (int qt = 0; qt < 2; ++qt)
#pragma unroll
        for (int kd = 0; kd < 2; ++kd)
            qf[qt][kd] = *(const bf16x8*)(Qp + (size_t)(q0 + qt * 16 + lr) * D + kd * 32 + lg * 8);

    const bf16 onev = (bf16)1.0f;
    const bf16x8 ones = { onev, onev, onev, onev, onev, onev, onev, onev };

    float mrow[2] = { -1e30f, -1e30f };   // running max (lane layout q = lr+16qt)
    float lrow[2][4] = {};                // denom  (cacc layout q = 4*lg+r)
    f32x4 cacc[2][4] = {};                // rows q = 4*lg + r, cols d = dt*16 + lr

    stage8(Kp, 64, &Kb[0][0][0], w * 8, lane);
    stage8(Vp, N,  &Vb[0][0][0], w * 8, lane);
    __syncthreads();
    int cur = 0;

    const int swz = (lr & 7) << 4;
    char* prow0 = (char*)&P[w][lr][0];

    for (int kt = 0; kt < N / 64; ++kt) {
        const int kk0 = kt * 64;
        if (kt + 1 < N / 64) {
            stage8(Kp + (size_t)(kk0 + 64) * 64, 64, &Kb[cur ^ 1][0][0], w * 8, lane);
            stage8(Vp + (kk0 + 64),         N,  &Vb[cur ^ 1][0][0], w * 8, lane);
        }
        const char* kbase = (const char*)&Kb[cur][0][0];
        f32x4 s[2][4] = {};
#pragma unroll
        for (int nt = 0; nt < 4; ++nt)
#pragma unroll
            for (int kd = 0; kd < 2; ++kd) {
                bf16x8 kf = *(const bf16x8*)(kbase + (nt * 16 + lr) * 128 + ((kd * 64 + lg * 16) ^ swz));
                s[0][nt] = __builtin_amdgcn_mfma_f32_16x16x32_bf16(kf, qf[0][kd], s[0][nt], 0, 0, 0);
                s[1][nt] = __builtin_amdgcn_mfma_f32_16x16x32_bf16(kf, qf[1][kd], s[1][nt], 0, 0, 0);
            }
        if (kk0 < q0 + 32 && q0 < kk0 + 64) {
#pragma unroll
            for (int qt = 0; qt < 2; ++qt) {
                int q = q0 + qt * 16 + lr;
#pragma unroll
                for (int nt = 0; nt < 4; ++nt)
#pragma unroll
                    for (int r = 0; r < 4; ++r)
                        if (kk0 + nt * 16 + lg * 4 + r == q) s[qt][nt][r] = -3e38f;
            }
        }
        float rm[2];
        bool need = false;
#pragma unroll
        for (int qt = 0; qt < 2; ++qt) {
            float v = s[qt][0][0];
#pragma unroll
            for (int nt = 0; nt < 4; ++nt)
#pragma unroll
                for (int r = 0; r < 4; ++r) v = fmaxf(v, s[qt][nt][r]);
            v = fmaxf(v, __shfl_xor(v, 16));
            v = fmaxf(v, __shfl_xor(v, 32));
            rm[qt] = v;
            need = need || (v > mrow[qt] + 64.f);
        }
        if (__any(need)) {
#pragma unroll
            for (int qt = 0; qt < 2; ++qt) {
                float mn = fmaxf(mrow[qt], rm[qt]);
                float f = exp2f((mrow[qt] - mn) * SCLOG);
                mrow[qt] = mn;
#pragma unroll
                for (int r = 0; r < 4; ++r) {
                    float fr = __shfl(f, lg * 4 + r);
                    lrow[qt][r] *= fr;
#pragma unroll
                    for (int dt = 0; dt < 4; ++dt) cacc[qt][dt][r] *= fr;
                }
            }
        }
        // ---- P = exp2((s - m)*SCLOG), pack b64 to LDS (swizzled)
#pragma unroll
        for (int qt = 0; qt < 2; ++qt) {
            float mc = mrow[qt] * SCLOG;
            char* prow = prow0 + qt * 2048;
#pragma unroll
            for (int nt = 0; nt < 4; ++nt) {
                float p0 = exp2f(__builtin_fmaf(s[qt][nt][0], SCLOG, -mc));
                float p1 = exp2f(__builtin_fmaf(s[qt][nt][1], SCLOG, -mc));
                float p2 = exp2f(__builtin_fmaf(s[qt][nt][2], SCLOG, -mc));
                float p3 = exp2f(__builtin_fmaf(s[qt][nt][3], SCLOG, -mc));
                bf16x4 pk = { (bf16)p0, (bf16)p1, (bf16)p2, (bf16)p3 };
                *(bf16x4*)(prow + ((nt * 32 + lg * 8) ^ swz)) = pk;
            }
        }
        // ---- ctx += P V ; row-sums via ones-MFMA
        const char* vbase = (const char*)&Vb[cur][0][0];
        f32x4 sacc[2] = {};
#pragma unroll
        for (int ks = 0; ks < 2; ++ks) {
            bf16x8 pa[2];
#pragma unroll
            for (int qt = 0; qt < 2; ++qt) {
                pa[qt] = *(const bf16x8*)(prow0 + qt * 2048 + ((ks * 64 + lg * 16) ^ swz));
                sacc[qt] = __builtin_amdgcn_mfma_f32_16x16x32_bf16(pa[qt], ones, sacc[qt], 0, 0, 0);
            }
#pragma unroll
            for (int dt = 0; dt < 4; ++dt) {
                bf16x8 vf = *(const bf16x8*)(vbase + (dt * 16 + lr) * 128 + ((ks * 64 + lg * 16) ^ swz));
                cacc[0][dt] = __builtin_amdgcn_mfma_f32_16x16x32_bf16(pa[0], vf, cacc[0][dt], 0, 0, 0);
                cacc[1][dt] = __builtin_amdgcn_mfma_f32_16x16x32_bf16(pa[1], vf, cacc[1][dt], 0, 0, 0);
            }
        }
#pragma unroll
        for (int qt = 0; qt < 2; ++qt)
#pragma unroll
            for (int r = 0; r < 4; ++r) lrow[qt][r] += sacc[qt][r];
        __syncthreads();
        cur ^= 1;
    }
    const int b = bh >> 3, h = bh & 7;
#pragma unroll
    for (int qt = 0; qt < 2; ++qt) {
#pragma unroll
        for (int r = 0; r < 4; ++r) {
            float oolr = 1.0f / lrow[qt][r];
            int q = q0 + qt * 16 + lg * 4 + r;
#pragma unroll
            for (int dt = 0; dt < 4; ++dt)
                ctx[((size_t)(b * N + q)) * HD + h * 64 + dt * 16 + lr] =
                    (bf16)(cacc[qt][dt][r] * oolr);
        }
    }
}

// ---------------- output projection ----------------
__global__ __launch_bounds__(256) void out_gemm(
    const bf16* __restrict__ ctx, const bf16* __restrict__ Wot,
    float* __restrict__ out) {
    const int w = threadIdx.x >> 6, lane = threadIdx.x & 63;
    const int lr = lane & 15, lg = lane >> 4;
    const int m0 = blockIdx.x * 64 + w * 16;
    f32x4 acc[4] = {};
#pragma unroll
    for (int ks = 0; ks < 16; ++ks) {
        bf16x8 af = *(const bf16x8*)(ctx + (size_t)(m0 + lr) * HD + ks * 32 + lg * 8);
#pragma unroll
        for (int nt = 0; nt < 4; ++nt) {
            bf16x8 wf = *(const bf16x8*)(Wot + (size_t)(nt * 16 + lr) * HD + ks * 32 + lg * 8);
            acc[nt] = __builtin_amdgcn_mfma_f32_16x16x32_bf16(af, wf, acc[nt], 0, 0, 0);
        }
    }
#pragma unroll
    for (int nt = 0; nt < 4; ++nt)
#pragma unroll
        for (int r = 0; r < 4; ++r)
            out[(size_t)(m0 + lg * 4 + r) * D + nt * 16 + lr] = acc[nt][r];
}

// ---------------- launcher ----------------
extern "C" void kernel_launch(void* const* d_in, const int* in_sizes, int n_in,
                              void* d_out, int out_size, void* d_ws, size_t ws_size,
                              hipStream_t stream) {
    (void)in_sizes; (void)n_in; (void)out_size; (void)ws_size;
    const float* msg = (const float*)d_in[0];
    const float* Wq  = (const float*)d_in[1];
    const float* bq  = (const float*)d_in[2];
    const float* Wk  = (const float*)d_in[3];
    const float* bk  = (const float*)d_in[4];
    const float* Wv  = (const float*)d_in[5];
    const float* bv  = (const float*)d_in[6];
    const float* Wo  = (const float*)d_in[7];
    float* out = (float*)d_out;

    char* p = (char*)d_ws;
    bf16*  Abf  = (bf16*)p;  p += (size_t)M * IN * 2;      // 8 MB
    bf16*  Wt   = (bf16*)p;  p += (size_t)QKV * IN * 2;    // 768 KB
    float* bias = (float*)p; p += (size_t)QKV * 4;         // 6 KB
    bf16*  Wot  = (bf16*)p;  p += (size_t)D * HD * 2;      // 64 KB
    bf16*  Qb   = (bf16*)p;  p += (size_t)Bsz * H * N * D * 2;   // 16 MB
    bf16*  Kb   = (bf16*)p;  p += (size_t)Bsz * H * N * D * 2;   // 16 MB
    bf16*  Vtb  = (bf16*)p;  p += (size_t)Bsz * H * D * N * 2;   // 16 MB
    bf16*  Ctx  = (bf16*)p;  p += (size_t)M * HD * 2;            // 16 MB

    cvt_msg<<<(M * IN / 4) / 256, 256, 0, stream>>>(msg, Abf);
    pack_w<<<417, 256, 0, stream>>>(Wq, Wk, Wv, bq, bk, bv, Wo, Wt, bias, Wot);

    dim3 g1(M / 128, QKV / 128);     // 128 x 12
    qkv_gemm<<<g1, 256, 0, stream>>>(Abf, Wt, bias, Qb, Kb, Vtb);

    dim3 g2(Bsz * H, N / 256);       // 64 x 8 : 512 blocks, 2/CU
    attn_kernel<<<g2, 512, 0, stream>>>(Qb, Kb, Vtb, Ctx);

    out_gemm<<<M / 64, 256, 0, stream>>>(Ctx, Wot, out);
}